// Round 18
// baseline (1441.675 us; speedup 1.0000x reference)
//
#include <hip/hip_runtime.h>
#include <hip/hip_fp16.h>
#include <cstdint>
#include <cstddef>

// Problem constants (setup_inputs: B=8,S=2048,D=768,E=8,I=3072,H=1536,top_k=2)
#define TK 16384   // tokens
#define DD 768
#define EE 8
#define II 3072
#define HH 1536

typedef _Float16 half8 __attribute__((ext_vector_type(8)));
typedef float floatx4 __attribute__((ext_vector_type(4)));

typedef const __attribute__((address_space(1))) uint32_t* gptr_t;
typedef __attribute__((address_space(3))) uint32_t* lptr_t;

#define GLOAD_LDS16(gp, lp) __builtin_amdgcn_global_load_lds( \
    (gptr_t)(const void*)(gp), (lptr_t)(void*)(lp), 16, 0, 0)

// Bijective XCD chunk swizzle (T1/m204). REV flips global order so the
// consumer reads the producer's FRESHEST output first (L3-resident tail).
__device__ __forceinline__ void xcd_swizzle(int& e, int& m, int& n, bool rev) {
  int gx = gridDim.x, gy = gridDim.y;
  int f = (blockIdx.z * gy + blockIdx.y) * gx + blockIdx.x;
  if (rev) f = gx * gy * 8 - 1 - f;
  int xcd = f & 7, idx = f >> 3;
  int chunk = idx / gx, pos = idx - chunk * gx;
  int logical = chunk * (8 * gx) + xcd * gx + pos;
  int mn = gy * gx;
  e = logical / mn;
  int rem = logical - e * mn;
  m = rem / gx;
  n = rem - m * gx;
}

// ------- fp32 [E][K][N] -> fp16 [E][N][K] transpose-convert (64x64 tiles) -------
__global__ __launch_bounds__(256)
void cvtT_kernel(const float* __restrict__ in, __half* __restrict__ out,
                 int K, int N) {
  __shared__ float tile[64][65];
  int e = blockIdx.z;
  const float* inp = in + (size_t)e * K * N + (size_t)(blockIdx.y * 64) * N + blockIdx.x * 64;
  __half* outp = out + (size_t)e * K * N + (size_t)(blockIdx.x * 64) * K + blockIdx.y * 64;
  int s = threadIdx.x;
  int tx = s & 15, r0 = s >> 4;           // tx: float4 col group, r0: row 0..15
#pragma unroll
  for (int i = 0; i < 4; ++i) {
    int k = r0 + i * 16;
    float4 v = *(const float4*)&inp[(size_t)k * N + tx * 4];
    tile[k][tx * 4 + 0] = v.x;
    tile[k][tx * 4 + 1] = v.y;
    tile[k][tx * 4 + 2] = v.z;
    tile[k][tx * 4 + 3] = v.w;
  }
  __syncthreads();
  int kp = s & 31;                         // k-pair 0..31
#pragma unroll
  for (int i = 0; i < 8; ++i) {
    int n = (s >> 5) + i * 8;
    __half2 h = __floats2half2_rn(tile[2 * kp][n], tile[2 * kp + 1][n]);
    *(__half2*)&outp[(size_t)n * K + kp * 2] = h;
  }
}

// ------- router: fp32 logits, top-2, softmax; also emits xh (fp16 copy of x) -------
__global__ __launch_bounds__(256)
void router_kernel(const float* __restrict__ x, const float* __restrict__ Wr,
                   const float* __restrict__ br, int* __restrict__ counts,
                   int* __restrict__ sel, float* __restrict__ wTok,
                   __half* __restrict__ xh) {
  __shared__ float wr_s[EE * DD];  // transposed [e][d], 24KB
  for (int i = threadIdx.x; i < EE * DD; i += 256) {
    int d = i >> 3, e = i & 7;
    wr_s[e * DD + d] = Wr[i];
  }
  __syncthreads();
  int wid = threadIdx.x >> 6, lane = threadIdx.x & 63;
  int t = blockIdx.x * 4 + wid;
  const float* xt = x + (size_t)t * DD;
  float acc[EE];
#pragma unroll
  for (int e = 0; e < EE; ++e) acc[e] = 0.f;
  for (int d = lane; d < DD; d += 64) {
    float xv = xt[d];
#pragma unroll
    for (int e = 0; e < EE; ++e) acc[e] += xv * wr_s[e * DD + d];
  }
#pragma unroll
  for (int off = 32; off > 0; off >>= 1)
#pragma unroll
    for (int e = 0; e < EE; ++e) acc[e] += __shfl_xor(acc[e], off);
  if (lane == 0) {
    float v[EE];
#pragma unroll
    for (int e = 0; e < EE; ++e) v[e] = acc[e] + br[e];
    int i0 = 0;
#pragma unroll
    for (int e = 1; e < EE; ++e) if (v[e] > v[i0]) i0 = e;
    int i1 = (i0 == 0) ? 1 : 0;
#pragma unroll
    for (int e = 0; e < EE; ++e) if (e != i0 && v[e] > v[i1] && e != i1) { if (v[e] > v[i1]) i1 = e; }
    float e1 = __expf(v[i1] - v[i0]);
    float s = 1.f / (1.f + e1);
    sel[2 * t] = i0; sel[2 * t + 1] = i1;
    wTok[2 * t] = s; wTok[2 * t + 1] = e1 * s;
    atomicAdd(&counts[i0], 1);
    atomicAdd(&counts[i1], 1);
  }
  // fused x -> fp16 conversion for this wave's token row
  const float4* xr = (const float4*)xt;
  uint2* xo = (uint2*)(xh + (size_t)t * DD);
#pragma unroll
  for (int j = 0; j < 3; ++j) {
    float4 v = xr[lane + j * 64];
    __half2 a = __floats2half2_rn(v.x, v.y);
    __half2 b = __floats2half2_rn(v.z, v.w);
    uint2 p;
    p.x = *(const unsigned int*)&a;
    p.y = *(const unsigned int*)&b;
    xo[lane + j * 64] = p;
  }
}

// ---------------- offsets (prefix over 8) ----------------
__global__ void offsets_kernel(const int* __restrict__ counts, int* __restrict__ offsets,
                               int* __restrict__ cursors) {
  if (threadIdx.x == 0) {
    int o = 0;
    for (int e = 0; e < EE; ++e) { offsets[e] = o; cursors[e] = o; o += counts[e]; }
  }
}

// ---------------- scatter token->slot ----------------
__global__ void scatter_kernel(const int* __restrict__ sel, int* __restrict__ cursors,
                               int* __restrict__ idxList, int* __restrict__ posTok) {
  int t = blockIdx.x * 256 + threadIdx.x;
  if (t < TK) {
#pragma unroll
    for (int k = 0; k < 2; ++k) {
      int e = sel[2 * t + k];
      int p = atomicAdd(&cursors[e], 1);
      idxList[p] = t;
      posTok[2 * t + k] = p;
    }
  }
}

// ======= BIG body (stages 1,2): 256x256, 8 waves, BK=32, ring A[5]+B[4] =======
// R12-proven. FIFO ledger: steady in-flight 14 loads; vmcnt(10) retires
// A(t+1),B(t+1); A staged 4 tiles ahead (~3600cy >> 900cy HBM miss).
// WAR: buf (t+4)%5 / (t+3)%4 last read at tile t-1, drained pre-barrier.
// s1 rationale (R18): at 128^2 tiles s1 re-reads ~2.4GB of L2/L3 panels
// (32xB + 24xA); 256^2 halves that, and s1 still has 1536 active blocks.
template<int KD, int ND, bool GATHER, bool GELU, bool REV>
__device__ __forceinline__
void ffn_body_big(const __half* __restrict__ A, const __half* __restrict__ Wt,
                  const float* __restrict__ Bias, __half* __restrict__ Out,
                  const int* __restrict__ counts, const int* __restrict__ offsets,
                  const int* __restrict__ idxList) {
  constexpr int NT = KD / 32;
  int e, mblk, nblk;
  xcd_swizzle(e, mblk, nblk, REV);
  const int cnt = counts[e];
  const int m0 = mblk * 256;
  if (cnt == 0 || m0 >= cnt) return;
  const int off = offsets[e];
  const int n0 = nblk * 256;
  const __half* We = Wt + (size_t)e * KD * ND;
  const float* be = Bias + (size_t)e * ND;

  __shared__ __align__(16) __half AsF[5 * 256 * 32];   // 80 KB
  __shared__ __align__(16) __half BsF[4 * 256 * 32];   // 64 KB

  const int tid = threadIdx.x;
  const int colh = (((tid & 3) ^ ((tid >> 3) & 3)) << 3);
  const __half* aptr2[2];
  const __half* bptr2[2];
#pragma unroll
  for (int i = 0; i < 2; ++i) {
    int r = i * 128 + (tid >> 2);
    int gr = m0 + r; if (gr > cnt - 1) gr = cnt - 1;
    size_t arow = GATHER ? (size_t)idxList[off + gr] : (size_t)(off + gr);
    aptr2[i] = A + arow * KD + colh;
    bptr2[i] = We + (size_t)(n0 + r) * KD + colh;
  }

#define STA(WOFF, TS) do { \
    GLOAD_LDS16(aptr2[0] + (TS) * 32, (char*)AsF + (WOFF) + tid * 16); \
    GLOAD_LDS16(aptr2[1] + (TS) * 32, (char*)AsF + (WOFF) + tid * 16 + 8192); } while (0)
#define STB(WOFF, TS) do { \
    GLOAD_LDS16(bptr2[0] + (TS) * 32, (char*)BsF + (WOFF) + tid * 16); \
    GLOAD_LDS16(bptr2[1] + (TS) * 32, (char*)BsF + (WOFF) + tid * 16 + 8192); } while (0)

  const int lane = tid & 63, wv = tid >> 6;
  const int wr = wv >> 2, wc = wv & 3;       // 2 x 4 wave grid
  const int lrow = lane & 15, lg = lane >> 4;
  const int slotSwz = lg ^ ((lrow >> 1) & 3);
  const int aBase = (wr * 128 + lrow) * 64 + slotSwz * 16;
  const int bBase = (wc * 64 + lrow) * 64 + slotSwz * 16;

  floatx4 acc[8][4];
#pragma unroll
  for (int mi = 0; mi < 8; ++mi)
#pragma unroll
    for (int ni = 0; ni < 4; ++ni) acc[mi][ni] = (floatx4){0.f, 0.f, 0.f, 0.f};

  STA(0 * 16384, 0);
  STB(0 * 16384, 0);
  STA(1 * 16384, 1);
  STB(1 * 16384, 1);
  STA(2 * 16384, 2);
  STB(2 * 16384, 2);
  STA(3 * 16384, 3);
  asm volatile("s_waitcnt vmcnt(10)" ::: "memory");
  __builtin_amdgcn_s_barrier();
  __builtin_amdgcn_sched_barrier(0);

  int rA = 0, wA = 4 * 16384;
  int rB = 0, wB = 3 * 16384;

#pragma unroll 1
  for (int t = 0; t < NT; ++t) {
    half8 af[8], bf[4];
#pragma unroll
    for (int mi = 0; mi < 8; ++mi)
      af[mi] = *(const half8*)((const char*)AsF + rA + aBase + mi * 1024);
#pragma unroll
    for (int ni = 0; ni < 4; ++ni)
      bf[ni] = *(const half8*)((const char*)BsF + rB + bBase + ni * 1024);
    if (t + 3 < NT) STB(wB, t + 3);
    if (t + 4 < NT) STA(wA, t + 4);
    __builtin_amdgcn_s_setprio(1);
#pragma unroll
    for (int mi = 0; mi < 8; ++mi)
#pragma unroll
      for (int ni = 0; ni < 4; ++ni)
        acc[mi][ni] = __builtin_amdgcn_mfma_f32_16x16x32_f16(
            af[mi], bf[ni], acc[mi][ni], 0, 0, 0);
    __builtin_amdgcn_s_setprio(0);
    if (t + 4 < NT) { asm volatile("s_waitcnt vmcnt(10)" ::: "memory"); }
    else            { asm volatile("s_waitcnt vmcnt(0)"  ::: "memory"); }
    __builtin_amdgcn_s_barrier();
    __builtin_amdgcn_sched_barrier(0);
    rA += 16384; if (rA == 5 * 16384) rA = 0;
    wA += 16384; if (wA == 5 * 16384) wA = 0;
    rB += 16384; if (rB == 4 * 16384) rB = 0;
    wB += 16384; if (wB == 4 * 16384) wB = 0;
  }

  const int crow = m0 + wr * 128 + lg * 4;
  const int ccol = n0 + wc * 64 + lrow;
  float bv[4];
#pragma unroll
  for (int ni = 0; ni < 4; ++ni) bv[ni] = be[ccol + ni * 16];
#pragma unroll
  for (int mi = 0; mi < 8; ++mi) {
#pragma unroll
    for (int j = 0; j < 4; ++j) {
      int r = crow + mi * 16 + j;
      if (r < cnt) {
#pragma unroll
        for (int ni = 0; ni < 4; ++ni) {
          float v = acc[mi][ni][j] + bv[ni];
          if (GELU) v = 0.5f * v * (1.f + erff(v * 0.70710678118654752f));
          Out[(size_t)(off + r) * ND + ccol + ni * 16] = __float2half(v);
        }
      }
    }
  }
#undef STA
#undef STB
}

// ======= SMALL body (stage 3): 128x128, 4 waves, BK=32, ring 3+3 =======
// R13-proven. vmcnt(4) retires tile t+1's 4 loads; ~3 blocks/CU TLP.
// s3 stays small: at 256^2 it would have only 384 active blocks (1.5/CU).
template<int KD, int ND, bool GATHER, bool GELU, bool REV>
__device__ __forceinline__
void ffn_body_small(const __half* __restrict__ A, const __half* __restrict__ Wt,
                    const float* __restrict__ Bias, __half* __restrict__ Out,
                    const int* __restrict__ counts, const int* __restrict__ offsets,
                    const int* __restrict__ idxList) {
  constexpr int NT = KD / 32;
  int e, mblk, nblk;
  xcd_swizzle(e, mblk, nblk, REV);
  const int cnt = counts[e];
  const int m0 = mblk * 128;
  if (cnt == 0 || m0 >= cnt) return;
  const int off = offsets[e];
  const int n0 = nblk * 128;
  const __half* We = Wt + (size_t)e * KD * ND;
  const float* be = Bias + (size_t)e * ND;

  __shared__ __align__(16) __half AsF[3 * 128 * 32];   // 24 KB
  __shared__ __align__(16) __half BsF[3 * 128 * 32];   // 24 KB

  const int tid = threadIdx.x;
  const int colh = (((tid & 3) ^ ((tid >> 3) & 3)) << 3);
  const __half* aptr2[2];
  const __half* bptr2[2];
#pragma unroll
  for (int i = 0; i < 2; ++i) {
    int r = i * 64 + (tid >> 2);
    int gr = m0 + r; if (gr > cnt - 1) gr = cnt - 1;
    size_t arow = GATHER ? (size_t)idxList[off + gr] : (size_t)(off + gr);
    aptr2[i] = A + arow * KD + colh;
    bptr2[i] = We + (size_t)(n0 + r) * KD + colh;
  }

#define STA(WOFF, TS) do { \
    GLOAD_LDS16(aptr2[0] + (TS) * 32, (char*)AsF + (WOFF) + tid * 16); \
    GLOAD_LDS16(aptr2[1] + (TS) * 32, (char*)AsF + (WOFF) + tid * 16 + 4096); } while (0)
#define STB(WOFF, TS) do { \
    GLOAD_LDS16(bptr2[0] + (TS) * 32, (char*)BsF + (WOFF) + tid * 16); \
    GLOAD_LDS16(bptr2[1] + (TS) * 32, (char*)BsF + (WOFF) + tid * 16 + 4096); } while (0)

  const int lane = tid & 63, wv = tid >> 6;
  const int wr = wv >> 1, wc = wv & 1;       // 2 x 2 wave grid
  const int lrow = lane & 15, lg = lane >> 4;
  const int slotSwz = lg ^ ((lrow >> 1) & 3);
  const int aBase = (wr * 64 + lrow) * 64 + slotSwz * 16;
  const int bBase = (wc * 64 + lrow) * 64 + slotSwz * 16;

  floatx4 acc[4][4];
#pragma unroll
  for (int mi = 0; mi < 4; ++mi)
#pragma unroll
    for (int ni = 0; ni < 4; ++ni) acc[mi][ni] = (floatx4){0.f, 0.f, 0.f, 0.f};

  STB(0, 0);
  STA(0, 0);
  STB(8192, 1);
  STA(8192, 1);
  asm volatile("s_waitcnt vmcnt(4)" ::: "memory");
  __builtin_amdgcn_s_barrier();
  __builtin_amdgcn_sched_barrier(0);

  int rBuf = 0, wBuf = 2 * 8192;

#pragma unroll 1
  for (int t = 0; t < NT; ++t) {
    half8 af[4], bf[4];
#pragma unroll
    for (int mi = 0; mi < 4; ++mi)
      af[mi] = *(const half8*)((const char*)AsF + rBuf + aBase + mi * 1024);
#pragma unroll
    for (int ni = 0; ni < 4; ++ni)
      bf[ni] = *(const half8*)((const char*)BsF + rBuf + bBase + ni * 1024);
    if (t + 2 < NT) { STB(wBuf, t + 2); STA(wBuf, t + 2); }
    __builtin_amdgcn_s_setprio(1);
#pragma unroll
    for (int mi = 0; mi < 4; ++mi)
#pragma unroll
      for (int ni = 0; ni < 4; ++ni)
        acc[mi][ni] = __builtin_amdgcn_mfma_f32_16x16x32_f16(
            af[mi], bf[ni], acc[mi][ni], 0, 0, 0);
    __builtin_amdgcn_s_setprio(0);
    if (t + 2 < NT) { asm volatile("s_waitcnt vmcnt(4)" ::: "memory"); }
    else            { asm volatile("s_waitcnt vmcnt(0)" ::: "memory"); }
    __builtin_amdgcn_s_barrier();
    __builtin_amdgcn_sched_barrier(0);
    rBuf += 8192; if (rBuf == 3 * 8192) rBuf = 0;
    wBuf += 8192; if (wBuf == 3 * 8192) wBuf = 0;
  }

  const int crow = m0 + wr * 64 + lg * 4;
  const int ccol = n0 + wc * 64 + lrow;
  float bv[4];
#pragma unroll
  for (int ni = 0; ni < 4; ++ni) bv[ni] = be[ccol + ni * 16];
#pragma unroll
  for (int mi = 0; mi < 4; ++mi) {
#pragma unroll
    for (int j = 0; j < 4; ++j) {
      int r = crow + mi * 16 + j;
      if (r < cnt) {
#pragma unroll
        for (int ni = 0; ni < 4; ++ni) {
          float v = acc[mi][ni][j] + bv[ni];
          if (GELU) v = 0.5f * v * (1.f + erff(v * 0.70710678118654752f));
          Out[(size_t)(off + r) * ND + ccol + ni * 16] = __float2half(v);
        }
      }
    }
  }
#undef STA
#undef STB
}

// Named per-stage kernels (rocprof attribution).
__global__ __launch_bounds__(512, 1)
void ffn_s1(const __half* __restrict__ A, const __half* __restrict__ Wt,
            const float* __restrict__ Bias, __half* __restrict__ Out,
            const int* __restrict__ counts, const int* __restrict__ offsets,
            const int* __restrict__ idxL) {
  ffn_body_big<DD, II, true, true, false>(A, Wt, Bias, Out, counts, offsets, idxL);
}
__global__ __launch_bounds__(512, 1)
void ffn_s2(const __half* __restrict__ A, const __half* __restrict__ Wt,
            const float* __restrict__ Bias, __half* __restrict__ Out,
            const int* __restrict__ counts, const int* __restrict__ offsets,
            const int* __restrict__ idxL) {
  // REV: read h1 freshest-first (L3 tail); writes h2 descending so stage-3's
  // ascending read order also hits freshest-first.
  ffn_body_big<II, HH, false, true, true>(A, Wt, Bias, Out, counts, offsets, idxL);
}
__global__ __launch_bounds__(256, 2)
void ffn_s3(const __half* __restrict__ A, const __half* __restrict__ Wt,
            const float* __restrict__ Bias, __half* __restrict__ Out,
            const int* __restrict__ counts, const int* __restrict__ offsets,
            const int* __restrict__ idxL) {
  ffn_body_small<HH, DD, false, false, false>(A, Wt, Bias, Out, counts, offsets, idxL);
}

// ---------------- combine: out[t] = w0*yc[p0] + w1*yc[p1] ----------------
__global__ void combine_kernel(const __half* __restrict__ yc, const float* __restrict__ wTok,
                               const int* __restrict__ posTok, float* __restrict__ out) {
  int t = blockIdx.x;
  int d = threadIdx.x * 4;
  if (d >= DD) return;
  float w0 = wTok[2 * t], w1 = wTok[2 * t + 1];
  const __half2* a = (const __half2*)(yc + (size_t)posTok[2 * t] * DD + d);
  const __half2* b = (const __half2*)(yc + (size_t)posTok[2 * t + 1] * DD + d);
  float2 a0 = __half22float2(a[0]), a1 = __half22float2(a[1]);
  float2 b0 = __half22float2(b[0]), b1 = __half22float2(b[1]);
  float4 r;
  r.x = w0 * a0.x + w1 * b0.x;
  r.y = w0 * a0.y + w1 * b0.y;
  r.z = w0 * a1.x + w1 * b1.x;
  r.w = w0 * a1.y + w1 * b1.y;
  *(float4*)(out + (size_t)t * DD + d) = r;
}

extern "C" void kernel_launch(void* const* d_in, const int* in_sizes, int n_in,
                              void* d_out, int out_size, void* d_ws, size_t ws_size,
                              hipStream_t stream) {
  const float* x  = (const float*)d_in[0];
  const float* Wr = (const float*)d_in[1];
  const float* br = (const float*)d_in[2];
  const float* W1 = (const float*)d_in[3];
  const float* b1 = (const float*)d_in[4];
  const float* W2 = (const float*)d_in[5];
  const float* b2 = (const float*)d_in[6];
  const float* W3 = (const float*)d_in[7];
  const float* b3 = (const float*)d_in[8];
  float* out = (float*)d_out;

  char* ws = (char*)d_ws;
  size_t o = 0;
  auto alloc = [&](size_t bytes) {
    char* p = ws + o;
    o += (bytes + 255) & ~(size_t)255;
    return p;
  };
  __half* xh   = (__half*)alloc((size_t)TK * DD * 2);
  __half* w1t  = (__half*)alloc((size_t)EE * DD * II * 2);
  __half* w2t  = (__half*)alloc((size_t)EE * II * HH * 2);
  __half* w3t  = (__half*)alloc((size_t)EE * HH * DD * 2);
  __half* h1   = (__half*)alloc((size_t)2 * TK * II * 2);
  __half* h2   = (__half*)alloc((size_t)2 * TK * HH * 2);
  __half* yc   = (__half*)alloc((size_t)2 * TK * DD * 2);
  int*   idxL  = (int*)alloc(2 * TK * 4);
  int*   sel   = (int*)alloc(2 * TK * 4);
  float* wTok  = (float*)alloc(2 * TK * 4);
  int*   posT  = (int*)alloc(2 * TK * 4);
  int*   counts  = (int*)alloc(256);
  int*   offsets = (int*)alloc(256);
  int*   cursors = (int*)alloc(256);
  if (o > ws_size) return;  // workspace too small -> loud absmax failure

  hipMemsetAsync(counts, 0, 256, stream);

  cvtT_kernel<<<dim3(II / 64, DD / 64, EE), 256, 0, stream>>>(W1, w1t, DD, II);
  cvtT_kernel<<<dim3(HH / 64, II / 64, EE), 256, 0, stream>>>(W2, w2t, II, HH);
  cvtT_kernel<<<dim3(DD / 64, HH / 64, EE), 256, 0, stream>>>(W3, w3t, HH, DD);
  router_kernel<<<TK / 4, 256, 0, stream>>>(x, Wr, br, counts, sel, wTok, xh);
  offsets_kernel<<<1, 64, 0, stream>>>(counts, offsets, cursors);
  scatter_kernel<<<TK / 256, 256, 0, stream>>>(sel, cursors, idxL, posT);

  ffn_s1<<<dim3(II / 256, 64, EE), 512, 0, stream>>>(xh, w1t, b1, h1, counts, offsets, idxL);
  ffn_s2<<<dim3(HH / 256, 64, EE), 512, 0, stream>>>(h1, w2t, b2, h2, counts, offsets, idxL);
  ffn_s3<<<dim3(DD / 128, 128, EE), 256, 0, stream>>>(h2, w3t, b3, yc, counts, offsets, idxL);

  combine_kernel<<<TK, 192, 0, stream>>>(yc, wTok, posT, out);
}

// Round 19
// 1424.887 us; speedup vs baseline: 1.0118x; 1.0118x over previous
//
#include <hip/hip_runtime.h>
#include <hip/hip_fp16.h>
#include <cstdint>
#include <cstddef>

// Problem constants (setup_inputs: B=8,S=2048,D=768,E=8,I=3072,H=1536,top_k=2)
#define TK 16384   // tokens
#define DD 768
#define EE 8
#define II 3072
#define HH 1536

typedef _Float16 half8 __attribute__((ext_vector_type(8)));
typedef float floatx4 __attribute__((ext_vector_type(4)));

typedef const __attribute__((address_space(1))) uint32_t* gptr_t;
typedef __attribute__((address_space(3))) uint32_t* lptr_t;

#define GLOAD_LDS16(gp, lp) __builtin_amdgcn_global_load_lds( \
    (gptr_t)(const void*)(gp), (lptr_t)(void*)(lp), 16, 0, 0)

// Bijective XCD chunk swizzle (T1/m204). REV flips global order so the
// consumer reads the producer's FRESHEST output first (L3-resident tail).
__device__ __forceinline__ void xcd_swizzle(int& e, int& m, int& n, bool rev) {
  int gx = gridDim.x, gy = gridDim.y;
  int f = (blockIdx.z * gy + blockIdx.y) * gx + blockIdx.x;
  if (rev) f = gx * gy * 8 - 1 - f;
  int xcd = f & 7, idx = f >> 3;
  int chunk = idx / gx, pos = idx - chunk * gx;
  int logical = chunk * (8 * gx) + xcd * gx + pos;
  int mn = gy * gx;
  e = logical / mn;
  int rem = logical - e * mn;
  m = rem / gx;
  n = rem - m * gx;
}

// ------- fp32 [E][K][N] -> fp16 [E][N][K] transpose-convert (64x64 tiles) -------
__global__ __launch_bounds__(256)
void cvtT_kernel(const float* __restrict__ in, __half* __restrict__ out,
                 int K, int N) {
  __shared__ float tile[64][65];
  int e = blockIdx.z;
  const float* inp = in + (size_t)e * K * N + (size_t)(blockIdx.y * 64) * N + blockIdx.x * 64;
  __half* outp = out + (size_t)e * K * N + (size_t)(blockIdx.x * 64) * K + blockIdx.y * 64;
  int s = threadIdx.x;
  int tx = s & 15, r0 = s >> 4;           // tx: float4 col group, r0: row 0..15
#pragma unroll
  for (int i = 0; i < 4; ++i) {
    int k = r0 + i * 16;
    float4 v = *(const float4*)&inp[(size_t)k * N + tx * 4];
    tile[k][tx * 4 + 0] = v.x;
    tile[k][tx * 4 + 1] = v.y;
    tile[k][tx * 4 + 2] = v.z;
    tile[k][tx * 4 + 3] = v.w;
  }
  __syncthreads();
  int kp = s & 31;                         // k-pair 0..31
#pragma unroll
  for (int i = 0; i < 8; ++i) {
    int n = (s >> 5) + i * 8;
    __half2 h = __floats2half2_rn(tile[2 * kp][n], tile[2 * kp + 1][n]);
    *(__half2*)&outp[(size_t)n * K + kp * 2] = h;
  }
}

// ------- router: fp32 logits, top-2, softmax; also emits xh (fp16 copy of x) -------
__global__ __launch_bounds__(256)
void router_kernel(const float* __restrict__ x, const float* __restrict__ Wr,
                   const float* __restrict__ br, int* __restrict__ counts,
                   int* __restrict__ sel, float* __restrict__ wTok,
                   __half* __restrict__ xh) {
  __shared__ float wr_s[EE * DD];  // transposed [e][d], 24KB
  for (int i = threadIdx.x; i < EE * DD; i += 256) {
    int d = i >> 3, e = i & 7;
    wr_s[e * DD + d] = Wr[i];
  }
  __syncthreads();
  int wid = threadIdx.x >> 6, lane = threadIdx.x & 63;
  int t = blockIdx.x * 4 + wid;
  const float* xt = x + (size_t)t * DD;
  float acc[EE];
#pragma unroll
  for (int e = 0; e < EE; ++e) acc[e] = 0.f;
  for (int d = lane; d < DD; d += 64) {
    float xv = xt[d];
#pragma unroll
    for (int e = 0; e < EE; ++e) acc[e] += xv * wr_s[e * DD + d];
  }
#pragma unroll
  for (int off = 32; off > 0; off >>= 1)
#pragma unroll
    for (int e = 0; e < EE; ++e) acc[e] += __shfl_xor(acc[e], off);
  if (lane == 0) {
    float v[EE];
#pragma unroll
    for (int e = 0; e < EE; ++e) v[e] = acc[e] + br[e];
    int i0 = 0;
#pragma unroll
    for (int e = 1; e < EE; ++e) if (v[e] > v[i0]) i0 = e;
    int i1 = (i0 == 0) ? 1 : 0;
#pragma unroll
    for (int e = 0; e < EE; ++e) if (e != i0 && v[e] > v[i1] && e != i1) { if (v[e] > v[i1]) i1 = e; }
    float e1 = __expf(v[i1] - v[i0]);
    float s = 1.f / (1.f + e1);
    sel[2 * t] = i0; sel[2 * t + 1] = i1;
    wTok[2 * t] = s; wTok[2 * t + 1] = e1 * s;
    atomicAdd(&counts[i0], 1);
    atomicAdd(&counts[i1], 1);
  }
  // fused x -> fp16 conversion for this wave's token row
  const float4* xr = (const float4*)xt;
  uint2* xo = (uint2*)(xh + (size_t)t * DD);
#pragma unroll
  for (int j = 0; j < 3; ++j) {
    float4 v = xr[lane + j * 64];
    __half2 a = __floats2half2_rn(v.x, v.y);
    __half2 b = __floats2half2_rn(v.z, v.w);
    uint2 p;
    p.x = *(const unsigned int*)&a;
    p.y = *(const unsigned int*)&b;
    xo[lane + j * 64] = p;
  }
}

// ---------------- offsets (prefix over 8) ----------------
__global__ void offsets_kernel(const int* __restrict__ counts, int* __restrict__ offsets,
                               int* __restrict__ cursors) {
  if (threadIdx.x == 0) {
    int o = 0;
    for (int e = 0; e < EE; ++e) { offsets[e] = o; cursors[e] = o; o += counts[e]; }
  }
}

// ---------------- scatter token->slot ----------------
__global__ void scatter_kernel(const int* __restrict__ sel, int* __restrict__ cursors,
                               int* __restrict__ idxList, int* __restrict__ posTok) {
  int t = blockIdx.x * 256 + threadIdx.x;
  if (t < TK) {
#pragma unroll
    for (int k = 0; k < 2; ++k) {
      int e = sel[2 * t + k];
      int p = atomicAdd(&cursors[e], 1);
      idxList[p] = t;
      posTok[2 * t + k] = p;
    }
  }
}

// ======= BIG body (stage 2): 256x256, 8 waves, BK=32, ring A[5]+B[4] =======
// R12-proven (433us on s2). FIFO ledger: steady in-flight 14 loads; vmcnt(10)
// retires A(t+1),B(t+1); A staged 4 tiles ahead (~3600cy >> 900cy HBM miss).
// WAR: buf (t+4)%5 / (t+3)%4 last read at tile t-1, drained pre-barrier.
template<int KD, int ND, bool GATHER, bool GELU, bool REV>
__device__ __forceinline__
void ffn_body_big(const __half* __restrict__ A, const __half* __restrict__ Wt,
                  const float* __restrict__ Bias, __half* __restrict__ Out,
                  const int* __restrict__ counts, const int* __restrict__ offsets,
                  const int* __restrict__ idxList) {
  constexpr int NT = KD / 32;
  int e, mblk, nblk;
  xcd_swizzle(e, mblk, nblk, REV);
  const int cnt = counts[e];
  const int m0 = mblk * 256;
  if (cnt == 0 || m0 >= cnt) return;
  const int off = offsets[e];
  const int n0 = nblk * 256;
  const __half* We = Wt + (size_t)e * KD * ND;
  const float* be = Bias + (size_t)e * ND;

  __shared__ __align__(16) __half AsF[5 * 256 * 32];   // 80 KB
  __shared__ __align__(16) __half BsF[4 * 256 * 32];   // 64 KB

  const int tid = threadIdx.x;
  const int colh = (((tid & 3) ^ ((tid >> 3) & 3)) << 3);
  const __half* aptr2[2];
  const __half* bptr2[2];
#pragma unroll
  for (int i = 0; i < 2; ++i) {
    int r = i * 128 + (tid >> 2);
    int gr = m0 + r; if (gr > cnt - 1) gr = cnt - 1;
    size_t arow = GATHER ? (size_t)idxList[off + gr] : (size_t)(off + gr);
    aptr2[i] = A + arow * KD + colh;
    bptr2[i] = We + (size_t)(n0 + r) * KD + colh;
  }

#define STA(WOFF, TS) do { \
    GLOAD_LDS16(aptr2[0] + (TS) * 32, (char*)AsF + (WOFF) + tid * 16); \
    GLOAD_LDS16(aptr2[1] + (TS) * 32, (char*)AsF + (WOFF) + tid * 16 + 8192); } while (0)
#define STB(WOFF, TS) do { \
    GLOAD_LDS16(bptr2[0] + (TS) * 32, (char*)BsF + (WOFF) + tid * 16); \
    GLOAD_LDS16(bptr2[1] + (TS) * 32, (char*)BsF + (WOFF) + tid * 16 + 8192); } while (0)

  const int lane = tid & 63, wv = tid >> 6;
  const int wr = wv >> 2, wc = wv & 3;       // 2 x 4 wave grid
  const int lrow = lane & 15, lg = lane >> 4;
  const int slotSwz = lg ^ ((lrow >> 1) & 3);
  const int aBase = (wr * 128 + lrow) * 64 + slotSwz * 16;
  const int bBase = (wc * 64 + lrow) * 64 + slotSwz * 16;

  floatx4 acc[8][4];
#pragma unroll
  for (int mi = 0; mi < 8; ++mi)
#pragma unroll
    for (int ni = 0; ni < 4; ++ni) acc[mi][ni] = (floatx4){0.f, 0.f, 0.f, 0.f};

  STA(0 * 16384, 0);
  STB(0 * 16384, 0);
  STA(1 * 16384, 1);
  STB(1 * 16384, 1);
  STA(2 * 16384, 2);
  STB(2 * 16384, 2);
  STA(3 * 16384, 3);
  asm volatile("s_waitcnt vmcnt(10)" ::: "memory");
  __builtin_amdgcn_s_barrier();
  __builtin_amdgcn_sched_barrier(0);

  int rA = 0, wA = 4 * 16384;
  int rB = 0, wB = 3 * 16384;

#pragma unroll 1
  for (int t = 0; t < NT; ++t) {
    half8 af[8], bf[4];
#pragma unroll
    for (int mi = 0; mi < 8; ++mi)
      af[mi] = *(const half8*)((const char*)AsF + rA + aBase + mi * 1024);
#pragma unroll
    for (int ni = 0; ni < 4; ++ni)
      bf[ni] = *(const half8*)((const char*)BsF + rB + bBase + ni * 1024);
    if (t + 3 < NT) STB(wB, t + 3);
    if (t + 4 < NT) STA(wA, t + 4);
    __builtin_amdgcn_s_setprio(1);
#pragma unroll
    for (int mi = 0; mi < 8; ++mi)
#pragma unroll
      for (int ni = 0; ni < 4; ++ni)
        acc[mi][ni] = __builtin_amdgcn_mfma_f32_16x16x32_f16(
            af[mi], bf[ni], acc[mi][ni], 0, 0, 0);
    __builtin_amdgcn_s_setprio(0);
    if (t + 4 < NT) { asm volatile("s_waitcnt vmcnt(10)" ::: "memory"); }
    else            { asm volatile("s_waitcnt vmcnt(0)"  ::: "memory"); }
    __builtin_amdgcn_s_barrier();
    __builtin_amdgcn_sched_barrier(0);
    rA += 16384; if (rA == 5 * 16384) rA = 0;
    wA += 16384; if (wA == 5 * 16384) wA = 0;
    rB += 16384; if (rB == 4 * 16384) rB = 0;
    wB += 16384; if (wB == 4 * 16384) wB = 0;
  }

  const int crow = m0 + wr * 128 + lg * 4;
  const int ccol = n0 + wc * 64 + lrow;
  float bv[4];
#pragma unroll
  for (int ni = 0; ni < 4; ++ni) bv[ni] = be[ccol + ni * 16];
#pragma unroll
  for (int mi = 0; mi < 8; ++mi) {
#pragma unroll
    for (int j = 0; j < 4; ++j) {
      int r = crow + mi * 16 + j;
      if (r < cnt) {
#pragma unroll
        for (int ni = 0; ni < 4; ++ni) {
          float v = acc[mi][ni][j] + bv[ni];
          if (GELU) v = 0.5f * v * (1.f + erff(v * 0.70710678118654752f));
          Out[(size_t)(off + r) * ND + ccol + ni * 16] = __float2half(v);
        }
      }
    }
  }
#undef STA
#undef STB
}

// ======= SMALL body (stages 1,3): 128x128, 4 waves, BK=32, ring 3+3 =======
// R13-proven. vmcnt(4) retires tile t+1's 4 loads; ~3 blocks/CU TLP.
template<int KD, int ND, bool GATHER, bool GELU, bool REV>
__device__ __forceinline__
void ffn_body_small(const __half* __restrict__ A, const __half* __restrict__ Wt,
                    const float* __restrict__ Bias, __half* __restrict__ Out,
                    const int* __restrict__ counts, const int* __restrict__ offsets,
                    const int* __restrict__ idxList) {
  constexpr int NT = KD / 32;
  int e, mblk, nblk;
  xcd_swizzle(e, mblk, nblk, REV);
  const int cnt = counts[e];
  const int m0 = mblk * 128;
  if (cnt == 0 || m0 >= cnt) return;
  const int off = offsets[e];
  const int n0 = nblk * 128;
  const __half* We = Wt + (size_t)e * KD * ND;
  const float* be = Bias + (size_t)e * ND;

  __shared__ __align__(16) __half AsF[3 * 128 * 32];   // 24 KB
  __shared__ __align__(16) __half BsF[3 * 128 * 32];   // 24 KB

  const int tid = threadIdx.x;
  const int colh = (((tid & 3) ^ ((tid >> 3) & 3)) << 3);
  const __half* aptr2[2];
  const __half* bptr2[2];
#pragma unroll
  for (int i = 0; i < 2; ++i) {
    int r = i * 64 + (tid >> 2);
    int gr = m0 + r; if (gr > cnt - 1) gr = cnt - 1;
    size_t arow = GATHER ? (size_t)idxList[off + gr] : (size_t)(off + gr);
    aptr2[i] = A + arow * KD + colh;
    bptr2[i] = We + (size_t)(n0 + r) * KD + colh;
  }

#define STA(WOFF, TS) do { \
    GLOAD_LDS16(aptr2[0] + (TS) * 32, (char*)AsF + (WOFF) + tid * 16); \
    GLOAD_LDS16(aptr2[1] + (TS) * 32, (char*)AsF + (WOFF) + tid * 16 + 4096); } while (0)
#define STB(WOFF, TS) do { \
    GLOAD_LDS16(bptr2[0] + (TS) * 32, (char*)BsF + (WOFF) + tid * 16); \
    GLOAD_LDS16(bptr2[1] + (TS) * 32, (char*)BsF + (WOFF) + tid * 16 + 4096); } while (0)

  const int lane = tid & 63, wv = tid >> 6;
  const int wr = wv >> 1, wc = wv & 1;       // 2 x 2 wave grid
  const int lrow = lane & 15, lg = lane >> 4;
  const int slotSwz = lg ^ ((lrow >> 1) & 3);
  const int aBase = (wr * 64 + lrow) * 64 + slotSwz * 16;
  const int bBase = (wc * 64 + lrow) * 64 + slotSwz * 16;

  floatx4 acc[4][4];
#pragma unroll
  for (int mi = 0; mi < 4; ++mi)
#pragma unroll
    for (int ni = 0; ni < 4; ++ni) acc[mi][ni] = (floatx4){0.f, 0.f, 0.f, 0.f};

  STB(0, 0);
  STA(0, 0);
  STB(8192, 1);
  STA(8192, 1);
  asm volatile("s_waitcnt vmcnt(4)" ::: "memory");
  __builtin_amdgcn_s_barrier();
  __builtin_amdgcn_sched_barrier(0);

  int rBuf = 0, wBuf = 2 * 8192;

#pragma unroll 1
  for (int t = 0; t < NT; ++t) {
    half8 af[4], bf[4];
#pragma unroll
    for (int mi = 0; mi < 4; ++mi)
      af[mi] = *(const half8*)((const char*)AsF + rBuf + aBase + mi * 1024);
#pragma unroll
    for (int ni = 0; ni < 4; ++ni)
      bf[ni] = *(const half8*)((const char*)BsF + rBuf + bBase + ni * 1024);
    if (t + 2 < NT) { STB(wBuf, t + 2); STA(wBuf, t + 2); }
    __builtin_amdgcn_s_setprio(1);
#pragma unroll
    for (int mi = 0; mi < 4; ++mi)
#pragma unroll
      for (int ni = 0; ni < 4; ++ni)
        acc[mi][ni] = __builtin_amdgcn_mfma_f32_16x16x32_f16(
            af[mi], bf[ni], acc[mi][ni], 0, 0, 0);
    __builtin_amdgcn_s_setprio(0);
    if (t + 2 < NT) { asm volatile("s_waitcnt vmcnt(4)" ::: "memory"); }
    else            { asm volatile("s_waitcnt vmcnt(0)" ::: "memory"); }
    __builtin_amdgcn_s_barrier();
    __builtin_amdgcn_sched_barrier(0);
    rBuf += 8192; if (rBuf == 3 * 8192) rBuf = 0;
    wBuf += 8192; if (wBuf == 3 * 8192) wBuf = 0;
  }

  const int crow = m0 + wr * 64 + lg * 4;
  const int ccol = n0 + wc * 64 + lrow;
  float bv[4];
#pragma unroll
  for (int ni = 0; ni < 4; ++ni) bv[ni] = be[ccol + ni * 16];
#pragma unroll
  for (int mi = 0; mi < 4; ++mi) {
#pragma unroll
    for (int j = 0; j < 4; ++j) {
      int r = crow + mi * 16 + j;
      if (r < cnt) {
#pragma unroll
        for (int ni = 0; ni < 4; ++ni) {
          float v = acc[mi][ni][j] + bv[ni];
          if (GELU) v = 0.5f * v * (1.f + erff(v * 0.70710678118654752f));
          Out[(size_t)(off + r) * ND + ccol + ni * 16] = __float2half(v);
        }
      }
    }
  }
#undef STA
#undef STB
}

// Named per-stage kernels (rocprof attribution).
__global__ __launch_bounds__(256, 2)
void ffn_s1(const __half* __restrict__ A, const __half* __restrict__ Wt,
            const float* __restrict__ Bias, __half* __restrict__ Out,
            const int* __restrict__ counts, const int* __restrict__ offsets,
            const int* __restrict__ idxL) {
  ffn_body_small<DD, II, true, true, false>(A, Wt, Bias, Out, counts, offsets, idxL);
}
__global__ __launch_bounds__(512, 1)
void ffn_s2(const __half* __restrict__ A, const __half* __restrict__ Wt,
            const float* __restrict__ Bias, __half* __restrict__ Out,
            const int* __restrict__ counts, const int* __restrict__ offsets,
            const int* __restrict__ idxL) {
  // REV: read h1 freshest-first (L3 tail); writes h2 descending so stage-3's
  // ascending read order also hits freshest-first.
  ffn_body_big<II, HH, false, true, true>(A, Wt, Bias, Out, counts, offsets, idxL);
}
__global__ __launch_bounds__(256, 2)
void ffn_s3(const __half* __restrict__ A, const __half* __restrict__ Wt,
            const float* __restrict__ Bias, __half* __restrict__ Out,
            const int* __restrict__ counts, const int* __restrict__ offsets,
            const int* __restrict__ idxL) {
  ffn_body_small<HH, DD, false, false, false>(A, Wt, Bias, Out, counts, offsets, idxL);
}

// ---------------- combine: out[t] = w0*yc[p0] + w1*yc[p1] ----------------
__global__ void combine_kernel(const __half* __restrict__ yc, const float* __restrict__ wTok,
                               const int* __restrict__ posTok, float* __restrict__ out) {
  int t = blockIdx.x;
  int d = threadIdx.x * 4;
  if (d >= DD) return;
  float w0 = wTok[2 * t], w1 = wTok[2 * t + 1];
  const __half2* a = (const __half2*)(yc + (size_t)posTok[2 * t] * DD + d);
  const __half2* b = (const __half2*)(yc + (size_t)posTok[2 * t + 1] * DD + d);
  float2 a0 = __half22float2(a[0]), a1 = __half22float2(a[1]);
  float2 b0 = __half22float2(b[0]), b1 = __half22float2(b[1]);
  float4 r;
  r.x = w0 * a0.x + w1 * b0.x;
  r.y = w0 * a0.y + w1 * b0.y;
  r.z = w0 * a1.x + w1 * b1.x;
  r.w = w0 * a1.y + w1 * b1.y;
  *(float4*)(out + (size_t)t * DD + d) = r;
}

extern "C" void kernel_launch(void* const* d_in, const int* in_sizes, int n_in,
                              void* d_out, int out_size, void* d_ws, size_t ws_size,
                              hipStream_t stream) {
  const float* x  = (const float*)d_in[0];
  const float* Wr = (const float*)d_in[1];
  const float* br = (const float*)d_in[2];
  const float* W1 = (const float*)d_in[3];
  const float* b1 = (const float*)d_in[4];
  const float* W2 = (const float*)d_in[5];
  const float* b2 = (const float*)d_in[6];
  const float* W3 = (const float*)d_in[7];
  const float* b3 = (const float*)d_in[8];
  float* out = (float*)d_out;

  char* ws = (char*)d_ws;
  size_t o = 0;
  auto alloc = [&](size_t bytes) {
    char* p = ws + o;
    o += (bytes + 255) & ~(size_t)255;
    return p;
  };
  __half* xh   = (__half*)alloc((size_t)TK * DD * 2);
  __half* w1t  = (__half*)alloc((size_t)EE * DD * II * 2);
  __half* w2t  = (__half*)alloc((size_t)EE * II * HH * 2);
  __half* w3t  = (__half*)alloc((size_t)EE * HH * DD * 2);
  __half* h1   = (__half*)alloc((size_t)2 * TK * II * 2);
  __half* h2   = (__half*)alloc((size_t)2 * TK * HH * 2);
  __half* yc   = (__half*)alloc((size_t)2 * TK * DD * 2);
  int*   idxL  = (int*)alloc(2 * TK * 4);
  int*   sel   = (int*)alloc(2 * TK * 4);
  float* wTok  = (float*)alloc(2 * TK * 4);
  int*   posT  = (int*)alloc(2 * TK * 4);
  int*   counts  = (int*)alloc(256);
  int*   offsets = (int*)alloc(256);
  int*   cursors = (int*)alloc(256);
  if (o > ws_size) return;  // workspace too small -> loud absmax failure

  hipMemsetAsync(counts, 0, 256, stream);

  cvtT_kernel<<<dim3(II / 64, DD / 64, EE), 256, 0, stream>>>(W1, w1t, DD, II);
  cvtT_kernel<<<dim3(HH / 64, II / 64, EE), 256, 0, stream>>>(W2, w2t, II, HH);
  cvtT_kernel<<<dim3(DD / 64, HH / 64, EE), 256, 0, stream>>>(W3, w3t, HH, DD);
  router_kernel<<<TK / 4, 256, 0, stream>>>(x, Wr, br, counts, sel, wTok, xh);
  offsets_kernel<<<1, 64, 0, stream>>>(counts, offsets, cursors);
  scatter_kernel<<<TK / 256, 256, 0, stream>>>(sel, cursors, idxL, posT);

  ffn_s1<<<dim3(II / 128, 128, EE), 256, 0, stream>>>(xh, w1t, b1, h1, counts, offsets, idxL);
  ffn_s2<<<dim3(HH / 256, 64, EE), 512, 0, stream>>>(h1, w2t, b2, h2, counts, offsets, idxL);
  ffn_s3<<<dim3(DD / 128, 128, EE), 256, 0, stream>>>(h2, w3t, b3, yc, counts, offsets, idxL);

  combine_kernel<<<TK, 192, 0, stream>>>(yc, wTok, posT, out);
}